// Round 3
// baseline (864.648 us; speedup 1.0000x reference)
//
#include <hip/hip_runtime.h>

#define HH 256
#define WW 256
#define HWPX 65536
#define BB 8
#define KK 21
#define CC 32

#define TW 32
#define TH 16
#define HALO_W (TW + 8)          // 40
#define HALO_H (TH + 8)          // 24
#define NHP (HALO_W * HALO_H)    // 960

typedef _Float16 half2v __attribute__((ext_vector_type(2)));
union F4H { float4 f4; half2v h[4]; };

// chunk j (8 channels = 16B) of halo pixel hp, swizzled so b128 reads/writes
// spread across all 32 banks (pos=(j+(hp>>1))&3 gives 8 distinct 4-bank
// groups over 8 consecutive hp).
__device__ __forceinline__ int swz(int hp, int j) {
    return hp * 4 + ((j + (hp >> 1)) & 3);
}

// ---------------- kernel 1: T[b,p] = sum_k S[b,k,p] ----------------
__global__ __launch_bounds__(256) void class_sum(const float* __restrict__ cls,
                                                 float* __restrict__ T) {
    int idx = blockIdx.x * 256 + threadIdx.x;
    int b = idx >> 16;
    int p = idx & (HWPX - 1);
    const float* base = cls + (size_t)b * KK * HWPX + p;
    float s = 0.f;
#pragma unroll
    for (int k = 0; k < KK; ++k) s += base[(size_t)k * HWPX];
    T[idx] = s;
}

// ---------------- kernel 2 (hot): LDS-tiled f16 affinity, 2 px/thread ----------------
__global__ __launch_bounds__(256, 2) void affinity2(const float* __restrict__ feat,
                                                    const float* __restrict__ T,
                                                    float* __restrict__ V,
                                                    float* __restrict__ deg) {
    __shared__ float4 tileF[NHP * 4];   // 60 KB: f16-packed pixel-major halo
    __shared__ float  tileT[NHP];       // 3.75 KB

    const int b   = blockIdx.z;
    const int gx0 = blockIdx.x * TW;
    const int gy0 = blockIdx.y * TH;
    const float* fb = feat + (size_t)b * CC * HWPX;
    const float* Tb = T + (size_t)b * HWPX;
    const int t = threadIdx.x;

    // ---- stage T halo (edge-clamped; invalid offsets masked later) ----
    for (int i = t; i < NHP; i += 256) {
        int hy = i / HALO_W;
        int hx = i - hy * HALO_W;
        int cy = min(max(gy0 + hy - 4, 0), HH - 1);
        int cx = min(max(gx0 + hx - 4, 0), WW - 1);
        tileT[i] = Tb[cy * WW + cx];
    }
    // ---- stage feature halo: 960 px x 4 chunks, f32 -> f16 pack ----
    for (int e = t; e < NHP * 4; e += 256) {
        int j  = e / NHP;            // channel chunk 0..3 (8 ch each)
        int hp = e - j * NHP;
        int hy = hp / HALO_W;
        int hx = hp - hy * HALO_W;
        int cy = min(max(gy0 + hy - 4, 0), HH - 1);
        int cx = min(max(gx0 + hx - 4, 0), WW - 1);
        const float* src = fb + (size_t)(j * 8) * HWPX + cy * WW + cx;
        F4H u;
#pragma unroll
        for (int k = 0; k < 4; ++k) {
            float a = src[(size_t)(2 * k) * HWPX];
            float c = src[(size_t)(2 * k + 1) * HWPX];
            u.h[k] = __builtin_bit_cast(half2v, __builtin_amdgcn_cvt_pkrtz(a, c));
        }
        tileF[swz(hp, j)] = u.f4;
    }
    __syncthreads();

    // thread owns vertical pixel pair A=(2ty, tx), B=(2ty+1, tx)
    const int tx  = t & 31;
    const int ty  = t >> 5;
    const int lx  = tx;
    const int lyA = 2 * ty;
    const int gx  = gx0 + lx;
    const int gyA = gy0 + lyA;

    const int hpA = (lyA + 4) * HALO_W + (lx + 4);
    const int hpB = hpA + HALO_W;
    F4H fA[4], fB[4];
#pragma unroll
    for (int j = 0; j < 4; ++j) {
        fA[j].f4 = tileF[swz(hpA, j)];
        fB[j].f4 = tileF[swz(hpB, j)];
    }

    float degA = 0.f, vA = 0.f, degB = 0.f, vB = 0.f;

    // union of offset circles of A and B(=A+(1,0)): dy in [-4,5], 78 loads
#pragma unroll
    for (int dy = -4; dy <= 5; ++dy) {
#pragma unroll
        for (int dx = -4; dx <= 4; ++dx) {
            const bool useA = (dy >= -4) && (dy <= 4) && (dy * dy + dx * dx < 25);
            const bool useB = ((dy - 1) * (dy - 1) + dx * dx < 25);
            if (!useA && !useB) continue;   // compile-time prune (78 survive)

            const int hp = hpA + dy * HALO_W + dx;
            F4H nb[4];
#pragma unroll
            for (int j = 0; j < 4; ++j) nb[j].f4 = tileF[swz(hp, j)];
            const float Tq = tileT[hp];
            // B's neighbor row is gyA+1+(dy-1) = gyA+dy -> same mask as A
            const bool valid = ((unsigned)(gyA + dy) < HH) && ((unsigned)(gx + dx) < WW);

            if (useA) {
                float d2 = 0.f;
#pragma unroll
                for (int j = 0; j < 4; ++j)
#pragma unroll
                    for (int k = 0; k < 4; ++k) {
                        half2v d = fA[j].h[k] - nb[j].h[k];
                        d2 = __builtin_amdgcn_fdot2(d, d, d2, false);
                    }
                float w = __expf((float)(-(dy * dy + dx * dx)) * 0.0625f - d2);
                w = valid ? w : 0.f;
                degA += w;
                vA = fmaf(w, Tq, vA);
            }
            if (useB) {
                float d2 = 0.f;
#pragma unroll
                for (int j = 0; j < 4; ++j)
#pragma unroll
                    for (int k = 0; k < 4; ++k) {
                        half2v d = fB[j].h[k] - nb[j].h[k];
                        d2 = __builtin_amdgcn_fdot2(d, d, d2, false);
                    }
                float w = __expf((float)(-((dy - 1) * (dy - 1) + dx * dx)) * 0.0625f - d2);
                w = valid ? w : 0.f;
                degB += w;
                vB = fmaf(w, Tq, vB);
            }
        }
    }

    const size_t idxA = (size_t)b * HWPX + (size_t)gyA * WW + gx;
    V[idxA] = vA;
    deg[idxA] = degA;
    V[idxA + WW] = vB;
    deg[idxA + WW] = degB;
}

// ---------------- kernel 3: per-(b,j) numer/denom reduction ----------------
__global__ __launch_bounds__(256) void reduce_bj(const float* __restrict__ cls,
                                                 const float* __restrict__ V,
                                                 const float* __restrict__ deg,
                                                 float* __restrict__ numer,
                                                 float* __restrict__ denom) {
    int b = blockIdx.y;
    int start = blockIdx.x * 256 + threadIdx.x;
    int stride = gridDim.x * 256;

    float accN[KK], accD[KK];
#pragma unroll
    for (int j = 0; j < KK; ++j) { accN[j] = 0.f; accD[j] = 0.f; }

    const float* clsb = cls + (size_t)b * KK * HWPX;
    const float* Vb = V + (size_t)b * HWPX;
    const float* db = deg + (size_t)b * HWPX;

    for (int p = start; p < HWPX; p += stride) {
        float v = Vb[p];
        float dg = db[p];
#pragma unroll
        for (int j = 0; j < KK; ++j) {
            float s = clsb[(size_t)j * HWPX + p];
            accN[j] = fmaf(s, v, accN[j]);
            accD[j] = fmaf(s, dg, accD[j]);
        }
    }

#pragma unroll
    for (int j = 0; j < KK; ++j) {
        float n = accN[j], d = accD[j];
#pragma unroll
        for (int off = 32; off > 0; off >>= 1) {
            n += __shfl_down(n, off);
            d += __shfl_down(d, off);
        }
        if ((threadIdx.x & 63) == 0) {
            atomicAdd(&numer[b * KK + j], n);
            atomicAdd(&denom[b * KK + j], d);
        }
    }
}

// ---------------- kernel 4: out = sum_{b,j} numer/denom ----------------
__global__ __launch_bounds__(256) void finalize(const float* __restrict__ numer,
                                                const float* __restrict__ denom,
                                                float* __restrict__ out) {
    __shared__ float sm[4];
    int i = threadIdx.x;
    float r = 0.f;
    if (i < BB * KK) r = numer[i] / denom[i];
#pragma unroll
    for (int off = 32; off > 0; off >>= 1) r += __shfl_down(r, off);
    if ((i & 63) == 0) sm[i >> 6] = r;
    __syncthreads();
    if (i == 0) out[0] = sm[0] + sm[1] + sm[2] + sm[3];
}

extern "C" void kernel_launch(void* const* d_in, const int* in_sizes, int n_in,
                              void* d_out, int out_size, void* d_ws, size_t ws_size,
                              hipStream_t stream) {
    const float* cls  = (const float*)d_in[0];  // [B,K,H,W]
    const float* feat = (const float*)d_in[1];  // [B,C,H,W]
    float* out = (float*)d_out;

    const size_t BHW = (size_t)BB * HWPX;
    float* T     = (float*)d_ws;
    float* V     = T + BHW;
    float* deg   = V + BHW;
    float* numer = deg + BHW;
    float* denom = numer + BB * KK;

    (void)hipMemsetAsync(numer, 0, 2 * BB * KK * sizeof(float), stream);

    class_sum<<<dim3(BB * HWPX / 256), dim3(256), 0, stream>>>(cls, T);
    affinity2<<<dim3(WW / TW, HH / TH, BB), dim3(256), 0, stream>>>(feat, T, V, deg);
    reduce_bj<<<dim3(32, BB), dim3(256), 0, stream>>>(cls, V, deg, numer, denom);
    finalize<<<dim3(1), dim3(256), 0, stream>>>(numer, denom, out);
}

// Round 4
// 397.148 us; speedup vs baseline: 2.1771x; 2.1771x over previous
//
#include <hip/hip_runtime.h>

#define HH 256
#define WW 256
#define HWPX 65536
#define BB 8
#define KK 21
#define CC 32

typedef _Float16 half2v __attribute__((ext_vector_type(2)));
union F4H { float4 f4; half2v h[4]; };

// ---------------- kernel 1: TN[b,p].x = sum_k S[b,k,p] ----------------
__global__ __launch_bounds__(256) void class_sum2(const float* __restrict__ cls,
                                                  float2* __restrict__ TN) {
    int idx = blockIdx.x * 256 + threadIdx.x;
    int b = idx >> 16;
    int p = idx & (HWPX - 1);
    const float* base = cls + (size_t)b * KK * HWPX + p;
    float s = 0.f;
#pragma unroll
    for (int k = 0; k < KK; ++k) s += base[(size_t)k * HWPX];
    TN[idx].x = s;
}

// ---------------- kernel 1b: pack features pixel-major f16 + |q|^2 ----------------
__global__ __launch_bounds__(256) void pack_feat(const float* __restrict__ feat,
                                                 float4* __restrict__ fpk,
                                                 float2* __restrict__ TN) {
    int idx = blockIdx.x * 256 + threadIdx.x;    // b*HWPX + p
    int b = idx >> 16;
    int p = idx & (HWPX - 1);
    const float* src = feat + (size_t)b * CC * HWPX + p;
    float nq = 0.f;
#pragma unroll
    for (int j = 0; j < 4; ++j) {
        F4H u;
#pragma unroll
        for (int k = 0; k < 4; ++k) {
            float a = src[(size_t)(j * 8 + 2 * k) * HWPX];
            float c = src[(size_t)(j * 8 + 2 * k + 1) * HWPX];
            u.h[k] = __builtin_bit_cast(half2v, __builtin_amdgcn_cvt_pkrtz(a, c));
            nq = __builtin_amdgcn_fdot2(u.h[k], u.h[k], nq, false);
        }
        fpk[(size_t)idx * 4 + j] = u.f4;
    }
    TN[idx].y = nq;
}

// ---------------- kernel 2 (hot): register-only affinity, pixel-major f16 ----------------
// w(p,q) = exp(-off^2/16 - (|p|^2 + |q|^2 - 2 p.q));  2*acc telescopes all terms.
__global__ __launch_bounds__(256) void affinity3(const float4* __restrict__ fpk,
                                                 const float2* __restrict__ TN,
                                                 float* __restrict__ V,
                                                 float* __restrict__ deg) {
    const int b  = blockIdx.z;
    const int tx = threadIdx.x & 63;
    const int ty = threadIdx.x >> 6;
    const int gx = blockIdx.x * 64 + tx;
    const int gy = blockIdx.y * 4 + ty;
    const int p  = (gy << 8) | gx;
    const float4* fb  = fpk + (size_t)b * HWPX * 4;
    const float2* tnb = TN + (size_t)b * HWPX;

    F4H fp[4];
#pragma unroll
    for (int j = 0; j < 4; ++j) fp[j].f4 = fb[(size_t)p * 4 + j];
    const float np_ = tnb[p].y;

    float degacc = 0.f, vacc = 0.f;

    // dxm per dy=-4..4 such that dy^2+dx^2 < 25 (69 evals total)
    const int DXM[9] = {2, 3, 4, 4, 4, 4, 4, 3, 2};

#pragma unroll 1   // runtime dy loop: caps load-hoisting window (round-3 spill lesson)
    for (int dyi = 0; dyi < 9; ++dyi) {
        const int dy = dyi - 4;
        const int gy2 = gy + dy;
        const bool rv = (unsigned)gy2 < HH;
        const int gy2c = min(max(gy2, 0), HH - 1);
        const int rowq = gy2c << 8;
        const int dxm = DXM[dyi];
        const float rowc = fmaf((float)(dy * dy), -0.03125f, -0.5f * np_);
#pragma unroll 1
        for (int dx = -dxm; dx <= dxm; ++dx) {
            const int gx2 = gx + dx;
            const bool valid = rv && ((unsigned)gx2 < WW);
            const int gx2c = min(max(gx2, 0), WW - 1);
            const int q = rowq | gx2c;

            const float4* qp = fb + (size_t)q * 4;
            F4H nb[4];
#pragma unroll
            for (int j = 0; j < 4; ++j) nb[j].f4 = qp[j];
            const float2 tq = tnb[q];

            float acc = fmaf(-0.5f, tq.y, rowc);
            acc = fmaf((float)(dx * dx), -0.03125f, acc);
#pragma unroll
            for (int j = 0; j < 4; ++j)
#pragma unroll
                for (int k = 0; k < 4; ++k)
                    acc = __builtin_amdgcn_fdot2(fp[j].h[k], nb[j].h[k], acc, false);

            float w = __builtin_exp2f(acc * 2.8853900817779268f);  // exp(2*acc)
            w = valid ? w : 0.f;
            degacc += w;
            vacc = fmaf(w, tq.x, vacc);
        }
    }
    const size_t o = (size_t)b * HWPX + p;
    V[o] = vacc;
    deg[o] = degacc;
}

// ---------------- fallback affinity (round-1, register/global, f32) ----------------
__global__ __launch_bounds__(256) void class_sum1(const float* __restrict__ cls,
                                                  float* __restrict__ T) {
    int idx = blockIdx.x * 256 + threadIdx.x;
    int b = idx >> 16;
    int p = idx & (HWPX - 1);
    const float* base = cls + (size_t)b * KK * HWPX + p;
    float s = 0.f;
#pragma unroll
    for (int k = 0; k < KK; ++k) s += base[(size_t)k * HWPX];
    T[idx] = s;
}

__global__ __launch_bounds__(256) void affinity1(const float* __restrict__ feat,
                                                 const float* __restrict__ T,
                                                 float* __restrict__ V,
                                                 float* __restrict__ deg) {
    int idx = blockIdx.x * 256 + threadIdx.x;
    int b = idx >> 16;
    int p = idx & (HWPX - 1);
    int h = p >> 8;
    int w = p & (WW - 1);
    const float* fb = feat + (size_t)b * CC * HWPX;
    float fp[CC];
#pragma unroll
    for (int c = 0; c < CC; ++c) fp[c] = fb[(size_t)c * HWPX + p];
    const float* Tb = T + b * HWPX;
    float degree = 0.f, v = 0.f;
#pragma unroll 1
    for (int dy = -4; dy <= 4; ++dy) {
        int h2 = h + dy;
        if ((unsigned)h2 >= HH) continue;
#pragma unroll
        for (int dx = -4; dx <= 4; ++dx) {
            if (dy * dy + dx * dx >= 25) continue;
            int w2 = w + dx;
            if ((unsigned)w2 >= WW) continue;
            int p2 = h2 * WW + w2;
            float d2 = 0.f;
#pragma unroll
            for (int c = 0; c < CC; ++c) {
                float df = fp[c] - fb[(size_t)c * HWPX + p2];
                d2 = fmaf(df, df, d2);
            }
            float wgt = __expf(-(float)(dy * dy + dx * dx) * 0.0625f - d2);
            degree += wgt;
            v = fmaf(wgt, Tb[p2], v);
        }
    }
    V[idx] = v;
    deg[idx] = degree;
}

// ---------------- kernel 3: per-(b,j) numer/denom reduction ----------------
__global__ __launch_bounds__(256) void reduce_bj(const float* __restrict__ cls,
                                                 const float* __restrict__ V,
                                                 const float* __restrict__ deg,
                                                 float* __restrict__ numer,
                                                 float* __restrict__ denom) {
    int b = blockIdx.y;
    int start = blockIdx.x * 256 + threadIdx.x;
    int stride = gridDim.x * 256;

    float accN[KK], accD[KK];
#pragma unroll
    for (int j = 0; j < KK; ++j) { accN[j] = 0.f; accD[j] = 0.f; }

    const float* clsb = cls + (size_t)b * KK * HWPX;
    const float* Vb = V + (size_t)b * HWPX;
    const float* db = deg + (size_t)b * HWPX;

    for (int p = start; p < HWPX; p += stride) {
        float v = Vb[p];
        float dg = db[p];
#pragma unroll
        for (int j = 0; j < KK; ++j) {
            float s = clsb[(size_t)j * HWPX + p];
            accN[j] = fmaf(s, v, accN[j]);
            accD[j] = fmaf(s, dg, accD[j]);
        }
    }

#pragma unroll
    for (int j = 0; j < KK; ++j) {
        float n = accN[j], d = accD[j];
#pragma unroll
        for (int off = 32; off > 0; off >>= 1) {
            n += __shfl_down(n, off);
            d += __shfl_down(d, off);
        }
        if ((threadIdx.x & 63) == 0) {
            atomicAdd(&numer[b * KK + j], n);
            atomicAdd(&denom[b * KK + j], d);
        }
    }
}

// ---------------- kernel 4: out = sum_{b,j} numer/denom ----------------
__global__ __launch_bounds__(256) void finalize(const float* __restrict__ numer,
                                                const float* __restrict__ denom,
                                                float* __restrict__ out) {
    __shared__ float sm[4];
    int i = threadIdx.x;
    float r = 0.f;
    if (i < BB * KK) r = numer[i] / denom[i];
#pragma unroll
    for (int off = 32; off > 0; off >>= 1) r += __shfl_down(r, off);
    if ((i & 63) == 0) sm[i >> 6] = r;
    __syncthreads();
    if (i == 0) out[0] = sm[0] + sm[1] + sm[2] + sm[3];
}

extern "C" void kernel_launch(void* const* d_in, const int* in_sizes, int n_in,
                              void* d_out, int out_size, void* d_ws, size_t ws_size,
                              hipStream_t stream) {
    const float* cls  = (const float*)d_in[0];  // [B,K,H,W]
    const float* feat = (const float*)d_in[1];  // [B,C,H,W]
    float* out = (float*)d_out;

    const size_t BHW = (size_t)BB * HWPX;
    // fast-path workspace: fpk (33.5 MB) | TN (4.2 MB) | V | deg | numer | denom
    const size_t NEED = BHW * 64 + BHW * 8 + BHW * 4 + BHW * 4 + 4 * BB * KK * 2;

    if (ws_size >= NEED) {
        float4* fpk  = (float4*)d_ws;
        float2* TN   = (float2*)((char*)d_ws + BHW * 64);
        float*  V    = (float*)((char*)TN + BHW * 8);
        float*  deg  = V + BHW;
        float*  numer = deg + BHW;
        float*  denom = numer + BB * KK;

        (void)hipMemsetAsync(numer, 0, 2 * BB * KK * sizeof(float), stream);
        class_sum2<<<dim3(BHW / 256), dim3(256), 0, stream>>>(cls, TN);
        pack_feat<<<dim3(BHW / 256), dim3(256), 0, stream>>>(feat, fpk, TN);
        affinity3<<<dim3(WW / 64, HH / 4, BB), dim3(256), 0, stream>>>(fpk, TN, V, deg);
        reduce_bj<<<dim3(64, BB), dim3(256), 0, stream>>>(cls, V, deg, numer, denom);
        finalize<<<dim3(1), dim3(256), 0, stream>>>(numer, denom, out);
    } else {
        // fallback: round-1 layout (~6.3 MB)
        float* T     = (float*)d_ws;
        float* V     = T + BHW;
        float* deg   = V + BHW;
        float* numer = deg + BHW;
        float* denom = numer + BB * KK;

        (void)hipMemsetAsync(numer, 0, 2 * BB * KK * sizeof(float), stream);
        class_sum1<<<dim3(BHW / 256), dim3(256), 0, stream>>>(cls, T);
        affinity1<<<dim3(BHW / 256), dim3(256), 0, stream>>>(feat, T, V, deg);
        reduce_bj<<<dim3(64, BB), dim3(256), 0, stream>>>(cls, V, deg, numer, denom);
        finalize<<<dim3(1), dim3(256), 0, stream>>>(numer, denom, out);
    }
}

// Round 5
// 279.933 us; speedup vs baseline: 3.0888x; 1.4187x over previous
//
#include <hip/hip_runtime.h>

#define HH 256
#define WW 256
#define HWPX 65536
#define BB 8
#define KK 21
#define CC 32

typedef _Float16 half2v __attribute__((ext_vector_type(2)));
union F4H { float4 f4; half2v h[4]; };

// ---------------- kernel 1 (fused): T + |q|^2 + planar f16 pack ----------------
// fpk layout: plane j (j=0..3, 8 channels each), plane stride BB*HWPX float4s.
// Within a plane: [b*HWPX + p] -> 16 B per pixel, lane-contiguous.
__global__ __launch_bounds__(256) void prep(const float* __restrict__ cls,
                                            const float* __restrict__ feat,
                                            float4* __restrict__ fpk,
                                            float2* __restrict__ TN) {
    int idx = blockIdx.x * 256 + threadIdx.x;    // b*HWPX + p
    int b = idx >> 16;
    int p = idx & (HWPX - 1);

    // T = sum_k S
    const float* cbase = cls + (size_t)b * KK * HWPX + p;
    float s = 0.f;
#pragma unroll
    for (int k = 0; k < KK; ++k) s += cbase[(size_t)k * HWPX];

    // pack features to f16 planes + accumulate |q|^2
    const float* src = feat + (size_t)b * CC * HWPX + p;
    float nq = 0.f;
#pragma unroll
    for (int j = 0; j < 4; ++j) {
        F4H u;
#pragma unroll
        for (int k = 0; k < 4; ++k) {
            float a = src[(size_t)(j * 8 + 2 * k) * HWPX];
            float c = src[(size_t)(j * 8 + 2 * k + 1) * HWPX];
            u.h[k] = __builtin_bit_cast(half2v, __builtin_amdgcn_cvt_pkrtz(a, c));
            nq = __builtin_amdgcn_fdot2(u.h[k], u.h[k], nq, false);
        }
        fpk[(size_t)j * (BB * HWPX) + idx] = u.f4;   // coalesced 16 B/lane
    }
    TN[idx] = make_float2(s, nq);                    // coalesced 8 B/lane
}

// ---------------- kernel 2 (hot): planar f16 affinity ----------------
// w(p,q) = exp(-off^2/16 - (|p|^2 + |q|^2 - 2 p.q)); acc telescopes, exp(2*acc).
__global__ __launch_bounds__(256, 8) void affinity3(const float4* __restrict__ fpk,
                                                    const float2* __restrict__ TN,
                                                    float* __restrict__ V,
                                                    float* __restrict__ deg) {
    const int b  = blockIdx.z;
    const int tx = threadIdx.x & 63;
    const int ty = threadIdx.x >> 6;
    const int gx = blockIdx.x * 64 + tx;
    const int gy = blockIdx.y * 4 + ty;
    const int p  = (gy << 8) | gx;
    const size_t bofs = (size_t)b * HWPX;
    const float4* fb0 = fpk + bofs;
    const float4* fb1 = fpk + (size_t)1 * BB * HWPX + bofs;
    const float4* fb2 = fpk + (size_t)2 * BB * HWPX + bofs;
    const float4* fb3 = fpk + (size_t)3 * BB * HWPX + bofs;
    const float2* tnb = TN + bofs;

    F4H fp[4];
    fp[0].f4 = fb0[p];
    fp[1].f4 = fb1[p];
    fp[2].f4 = fb2[p];
    fp[3].f4 = fb3[p];
    const float np_ = tnb[p].y;

    float degacc = 0.f, vacc = 0.f;

    // dx extent per dy=-4..4 such that dy^2+dx^2 < 25 (69 evals total)
    const int DXM[9] = {2, 3, 4, 4, 4, 4, 4, 3, 2};

#pragma unroll 1   // runtime dy loop: caps load-hoisting window (round-3 spill lesson)
    for (int dyi = 0; dyi < 9; ++dyi) {
        const int dy = dyi - 4;
        const int gy2 = gy + dy;
        const bool rv = (unsigned)gy2 < HH;
        const int gy2c = min(max(gy2, 0), HH - 1);
        const int rowq = gy2c << 8;
        const int dxm = DXM[dyi];
        const float rowc = fmaf((float)(dy * dy), -0.03125f, -0.5f * np_);
#pragma unroll 2
        for (int dx = -dxm; dx <= dxm; ++dx) {
            const int gx2 = gx + dx;
            const bool valid = rv && ((unsigned)gx2 < WW);
            const int gx2c = min(max(gx2, 0), WW - 1);
            const int q = rowq | gx2c;

            F4H nb[4];
            nb[0].f4 = fb0[q];
            nb[1].f4 = fb1[q];
            nb[2].f4 = fb2[q];
            nb[3].f4 = fb3[q];
            const float2 tq = tnb[q];

            float acc = fmaf(-0.5f, tq.y, rowc);
            acc = fmaf((float)(dx * dx), -0.03125f, acc);
#pragma unroll
            for (int j = 0; j < 4; ++j)
#pragma unroll
                for (int k = 0; k < 4; ++k)
                    acc = __builtin_amdgcn_fdot2(fp[j].h[k], nb[j].h[k], acc, false);

            float w = __builtin_exp2f(acc * 2.8853900817779268f);  // exp(2*acc)
            w = valid ? w : 0.f;
            degacc += w;
            vacc = fmaf(w, tq.x, vacc);
        }
    }
    const size_t o = bofs + p;
    V[o] = vacc;
    deg[o] = degacc;
}

// ---------------- kernel 3: per-(b,j) numer/denom reduction ----------------
__global__ __launch_bounds__(256) void reduce_bj(const float* __restrict__ cls,
                                                 const float* __restrict__ V,
                                                 const float* __restrict__ deg,
                                                 float* __restrict__ numer,
                                                 float* __restrict__ denom) {
    __shared__ float smN[4][22], smD[4][22];   // +1 pad
    int b = blockIdx.y;
    int start = blockIdx.x * 256 + threadIdx.x;
    int stride = gridDim.x * 256;

    float accN[KK], accD[KK];
#pragma unroll
    for (int j = 0; j < KK; ++j) { accN[j] = 0.f; accD[j] = 0.f; }

    const float* clsb = cls + (size_t)b * KK * HWPX;
    const float* Vb = V + (size_t)b * HWPX;
    const float* db = deg + (size_t)b * HWPX;

    for (int p = start; p < HWPX; p += stride) {
        float v = Vb[p];
        float dg = db[p];
#pragma unroll
        for (int j = 0; j < KK; ++j) {
            float s = clsb[(size_t)j * HWPX + p];
            accN[j] = fmaf(s, v, accN[j]);
            accD[j] = fmaf(s, dg, accD[j]);
        }
    }

    const int wid = threadIdx.x >> 6;
#pragma unroll
    for (int j = 0; j < KK; ++j) {
        float n = accN[j], d = accD[j];
#pragma unroll
        for (int off = 32; off > 0; off >>= 1) {
            n += __shfl_down(n, off);
            d += __shfl_down(d, off);
        }
        if ((threadIdx.x & 63) == 0) { smN[wid][j] = n; smD[wid][j] = d; }
    }
    __syncthreads();
    // 42 atomics per block (one per lane), not 168
    if (threadIdx.x < 2 * KK) {
        int half = threadIdx.x / KK;       // 0 = numer, 1 = denom
        int j = threadIdx.x - half * KK;
        float acc = half ? (smD[0][j] + smD[1][j] + smD[2][j] + smD[3][j])
                         : (smN[0][j] + smN[1][j] + smN[2][j] + smN[3][j]);
        float* dst = half ? denom : numer;
        atomicAdd(&dst[b * KK + j], acc);
    }
}

// ---------------- kernel 4: out = sum_{b,j} numer/denom ----------------
__global__ __launch_bounds__(256) void finalize(const float* __restrict__ numer,
                                                const float* __restrict__ denom,
                                                float* __restrict__ out) {
    __shared__ float sm[4];
    int i = threadIdx.x;
    float r = 0.f;
    if (i < BB * KK) r = numer[i] / denom[i];
#pragma unroll
    for (int off = 32; off > 0; off >>= 1) r += __shfl_down(r, off);
    if ((i & 63) == 0) sm[i >> 6] = r;
    __syncthreads();
    if (i == 0) out[0] = sm[0] + sm[1] + sm[2] + sm[3];
}

extern "C" void kernel_launch(void* const* d_in, const int* in_sizes, int n_in,
                              void* d_out, int out_size, void* d_ws, size_t ws_size,
                              hipStream_t stream) {
    const float* cls  = (const float*)d_in[0];  // [B,K,H,W]
    const float* feat = (const float*)d_in[1];  // [B,C,H,W]
    float* out = (float*)d_out;

    const size_t BHW = (size_t)BB * HWPX;
    // fpk (33.5 MB) | TN (4.2 MB) | V | deg | numer | denom   (~42 MB)
    float4* fpk  = (float4*)d_ws;
    float2* TN   = (float2*)((char*)d_ws + BHW * 64);
    float*  V    = (float*)((char*)TN + BHW * 8);
    float*  deg  = V + BHW;
    float*  numer = deg + BHW;
    float*  denom = numer + BB * KK;

    (void)hipMemsetAsync(numer, 0, 2 * BB * KK * sizeof(float), stream);
    prep<<<dim3(BHW / 256), dim3(256), 0, stream>>>(cls, feat, fpk, TN);
    affinity3<<<dim3(WW / 64, HH / 4, BB), dim3(256), 0, stream>>>(fpk, TN, V, deg);
    reduce_bj<<<dim3(64, BB), dim3(256), 0, stream>>>(cls, V, deg, numer, denom);
    finalize<<<dim3(1), dim3(256), 0, stream>>>(numer, denom, out);
}

// Round 6
// 205.880 us; speedup vs baseline: 4.1998x; 1.3597x over previous
//
#include <hip/hip_runtime.h>

#define HH 256
#define WW 256
#define HWPX 65536
#define BB 8
#define KK 21
#define CC 32

typedef _Float16 half2v __attribute__((ext_vector_type(2)));
union F4H { float4 f4; half2v h[4]; };

// ---------------- kernel 1 (fused): T + |q|^2 + planar f16 pack, 4 px/thread ----------------
// fpk layout: plane j (8 channels), plane stride BB*HWPX float4s; within plane
// [global pixel idx] -> 16 B, lane-contiguous.
__global__ __launch_bounds__(256) void prep(const float* __restrict__ cls,
                                            const float* __restrict__ feat,
                                            float4* __restrict__ fpk,
                                            float2* __restrict__ TN) {
    const int tid = blockIdx.x * 256 + threadIdx.x;   // 0..131071
    const int p4 = tid * 4;                            // global pixel idx (b*HWPX+p)
    const int b = p4 >> 16;
    const int p = p4 & (HWPX - 1);

    // T = sum_k S, 4 px at once (float4 loads, 16 B/lane)
    const float* cbase = cls + (size_t)b * KK * HWPX + p;
    float4 s = make_float4(0.f, 0.f, 0.f, 0.f);
#pragma unroll
    for (int k = 0; k < KK; ++k) {
        float4 c = *(const float4*)(cbase + (size_t)k * HWPX);
        s.x += c.x; s.y += c.y; s.z += c.z; s.w += c.w;
    }

    const float* src = feat + (size_t)b * CC * HWPX + p;
    float nq[4] = {0.f, 0.f, 0.f, 0.f};
#pragma unroll
    for (int j = 0; j < 4; ++j) {
        float4 ch[8];
#pragma unroll
        for (int c = 0; c < 8; ++c)
            ch[c] = *(const float4*)(src + (size_t)(j * 8 + c) * HWPX);
#pragma unroll
        for (int px = 0; px < 4; ++px) {
            F4H u;
#pragma unroll
            for (int k = 0; k < 4; ++k) {
                float a  = ((const float*)&ch[2 * k])[px];
                float b2 = ((const float*)&ch[2 * k + 1])[px];
                u.h[k] = __builtin_bit_cast(half2v, __builtin_amdgcn_cvt_pkrtz(a, b2));
                nq[px] = __builtin_amdgcn_fdot2(u.h[k], u.h[k], nq[px], false);
            }
            fpk[(size_t)j * (BB * HWPX) + p4 + px] = u.f4;
        }
    }
    const float* sa = (const float*)&s;
#pragma unroll
    for (int px = 0; px < 4; ++px) TN[p4 + px] = make_float2(sa[px], nq[px]);
}

// ---------------- kernel 2 (hot): planar f16 affinity, 4 stacked px/thread ----------------
// w(p,q) = exp(-off^2/16 - (|p|^2+|q|^2-2 p.q)); acc telescopes, w = exp2(2*log2e*acc).
__global__ __launch_bounds__(256) void affinity4(const float4* __restrict__ fpk,
                                                 const float2* __restrict__ TN,
                                                 float* __restrict__ V,
                                                 float* __restrict__ deg) {
    // XCD swizzle: L%8 = batch so each XCD's round-robin share is one batch (~4.7 MB, L2-resident)
    const int L  = blockIdx.x;            // 0..511
    const int b  = L & 7;
    const int t  = L >> 3;
    const int by = t & 15;
    const int bx = t >> 4;                // 0..3
    const int lane = threadIdx.x & 63;
    const int wid  = threadIdx.x >> 6;
    const int gx  = bx * 64 + lane;
    const int gy0 = by * 16 + wid * 4;    // owns rows gy0..gy0+3

    const size_t bofs = (size_t)b * HWPX;
    const float4* fb0 = fpk + bofs;
    const float4* fb1 = fpk + (size_t)1 * BB * HWPX + bofs;
    const float4* fb2 = fpk + (size_t)2 * BB * HWPX + bofs;
    const float4* fb3 = fpk + (size_t)3 * BB * HWPX + bofs;
    const float2* tnb = TN + bofs;

    F4H fp[4][4];
    float np_[4];
#pragma unroll
    for (int py = 0; py < 4; ++py) {
        const int pp = ((gy0 + py) << 8) | gx;
        fp[py][0].f4 = fb0[pp];
        fp[py][1].f4 = fb1[pp];
        fp[py][2].f4 = fb2[pp];
        fp[py][3].f4 = fb3[pp];
        np_[py] = tnb[pp].y;
    }

    float degacc[4] = {0.f, 0.f, 0.f, 0.f};
    float vacc[4]   = {0.f, 0.f, 0.f, 0.f};

#pragma unroll 1   // runtime row loop: caps load-hoisting window (round-3 spill lesson)
    for (int dyi = 0; dyi < 12; ++dyi) {
        const int ny = gy0 + dyi - 4;               // neighbor row, same for all py
        if ((unsigned)ny >= HH) continue;           // uniform: OOB row contributes 0
        const int rowq = ny << 8;

        int dy2[4];
        float base[4];
#pragma unroll
        for (int py = 0; py < 4; ++py) {
            const int d = dyi - 4 - py;             // uniform
            dy2[py] = d * d;
            base[py] = fmaf(-0.03125f, (float)dy2[py], -0.5f * np_[py]);
        }
        const int mind = min(min(dy2[0], dy2[1]), min(dy2[2], dy2[3]));

#pragma unroll 3
        for (int dxi = 0; dxi < 9; ++dxi) {
            const int dx = dxi - 4;                 // uniform
            const int dx2 = dx * dx;
            if (mind + dx2 >= 25) continue;         // uniform: no py uses this column

            const int gx2 = gx + dx;
            const bool vx = (unsigned)gx2 < WW;     // per-lane x bound
            const int q = rowq | min(max(gx2, 0), WW - 1);

            F4H nb0, nb1, nb2, nb3;
            nb0.f4 = fb0[q];
            nb1.f4 = fb1[q];
            nb2.f4 = fb2[q];
            nb3.f4 = fb3[q];
            const float2 tq = tnb[q];
            const float cdx = (float)dx2 * -0.03125f;

#pragma unroll
            for (int py = 0; py < 4; ++py) {
                if (dy2[py] + dx2 < 25) {           // uniform circle test
                    float acc = fmaf(-0.5f, tq.y, base[py] + cdx);
#pragma unroll
                    for (int k = 0; k < 4; ++k) {
                        acc = __builtin_amdgcn_fdot2(fp[py][0].h[k], nb0.h[k], acc, false);
                        acc = __builtin_amdgcn_fdot2(fp[py][1].h[k], nb1.h[k], acc, false);
                        acc = __builtin_amdgcn_fdot2(fp[py][2].h[k], nb2.h[k], acc, false);
                        acc = __builtin_amdgcn_fdot2(fp[py][3].h[k], nb3.h[k], acc, false);
                    }
                    float w = __builtin_exp2f(acc * 2.8853900817779268f);  // exp(2*acc)
                    w = vx ? w : 0.f;
                    degacc[py] += w;
                    vacc[py] = fmaf(w, tq.x, vacc[py]);
                }
            }
        }
    }

#pragma unroll
    for (int py = 0; py < 4; ++py) {
        const size_t o = bofs + ((size_t)(gy0 + py) << 8) + gx;
        V[o] = vacc[py];
        deg[o] = degacc[py];
    }
}

// ---------------- kernel 3: per-(b,j) numer/denom, single pass, 4 px/thread ----------------
__global__ __launch_bounds__(256) void reduce_bj(const float* __restrict__ cls,
                                                 const float* __restrict__ V,
                                                 const float* __restrict__ deg,
                                                 float* __restrict__ numer,
                                                 float* __restrict__ denom) {
    __shared__ float smN[4][22], smD[4][22];
    const int b = blockIdx.y;
    const int p4 = (blockIdx.x * 256 + threadIdx.x) * 4;   // grid.x=64 covers HWPX

    const float* clsb = cls + (size_t)b * KK * HWPX;
    const float4 v4 = *(const float4*)(V + (size_t)b * HWPX + p4);
    const float4 d4 = *(const float4*)(deg + (size_t)b * HWPX + p4);

    float accN[KK], accD[KK];
#pragma unroll
    for (int j = 0; j < KK; ++j) {
        float4 s4 = *(const float4*)(clsb + (size_t)j * HWPX + p4);
        float n = s4.x * v4.x;  n = fmaf(s4.y, v4.y, n);
        n = fmaf(s4.z, v4.z, n); n = fmaf(s4.w, v4.w, n);
        float d = s4.x * d4.x;  d = fmaf(s4.y, d4.y, d);
        d = fmaf(s4.z, d4.z, d); d = fmaf(s4.w, d4.w, d);
        accN[j] = n; accD[j] = d;
    }

    const int wid = threadIdx.x >> 6;
#pragma unroll
    for (int j = 0; j < KK; ++j) {
        float n = accN[j], d = accD[j];
#pragma unroll
        for (int off = 32; off > 0; off >>= 1) {
            n += __shfl_down(n, off);
            d += __shfl_down(d, off);
        }
        if ((threadIdx.x & 63) == 0) { smN[wid][j] = n; smD[wid][j] = d; }
    }
    __syncthreads();
    if (threadIdx.x < 2 * KK) {
        int half = threadIdx.x / KK;
        int j = threadIdx.x - half * KK;
        float acc = half ? (smD[0][j] + smD[1][j] + smD[2][j] + smD[3][j])
                         : (smN[0][j] + smN[1][j] + smN[2][j] + smN[3][j]);
        float* dst = half ? denom : numer;
        atomicAdd(&dst[b * KK + j], acc);
    }
}

// ---------------- kernel 4: out = sum_{b,j} numer/denom ----------------
__global__ __launch_bounds__(256) void finalize(const float* __restrict__ numer,
                                                const float* __restrict__ denom,
                                                float* __restrict__ out) {
    __shared__ float sm[4];
    int i = threadIdx.x;
    float r = 0.f;
    if (i < BB * KK) r = numer[i] / denom[i];
#pragma unroll
    for (int off = 32; off > 0; off >>= 1) r += __shfl_down(r, off);
    if ((i & 63) == 0) sm[i >> 6] = r;
    __syncthreads();
    if (i == 0) out[0] = sm[0] + sm[1] + sm[2] + sm[3];
}

extern "C" void kernel_launch(void* const* d_in, const int* in_sizes, int n_in,
                              void* d_out, int out_size, void* d_ws, size_t ws_size,
                              hipStream_t stream) {
    const float* cls  = (const float*)d_in[0];  // [B,K,H,W]
    const float* feat = (const float*)d_in[1];  // [B,C,H,W]
    float* out = (float*)d_out;

    const size_t BHW = (size_t)BB * HWPX;
    // fpk (33.5 MB) | TN (4.2 MB) | V | deg | numer | denom   (~42 MB)
    float4* fpk  = (float4*)d_ws;
    float2* TN   = (float2*)((char*)d_ws + BHW * 64);
    float*  V    = (float*)((char*)TN + BHW * 8);
    float*  deg  = V + BHW;
    float*  numer = deg + BHW;
    float*  denom = numer + BB * KK;

    (void)hipMemsetAsync(numer, 0, 2 * BB * KK * sizeof(float), stream);
    prep<<<dim3(BHW / 1024), dim3(256), 0, stream>>>(cls, feat, fpk, TN);
    affinity4<<<dim3(512), dim3(256), 0, stream>>>(fpk, TN, V, deg);
    reduce_bj<<<dim3(HWPX / 1024, BB), dim3(256), 0, stream>>>(cls, V, deg, numer, denom);
    finalize<<<dim3(1), dim3(256), 0, stream>>>(numer, denom, out);
}